// Round 5
// baseline (1217.332 us; speedup 1.0000x reference)
//
#include <hip/hip_runtime.h>

typedef unsigned short u16;
typedef unsigned int u32;
typedef unsigned char u8t;
using bfrag = __attribute__((ext_vector_type(8))) short;   // 8 x bf16 (raw bits)
using facc  = __attribute__((ext_vector_type(4))) float;   // MFMA accumulator

// ---------------- numeric helpers ----------------
__device__ __forceinline__ u16 f2b(float f) {              // f32 -> bf16 (RNE)
  u32 u = __float_as_uint(f);
  return (u16)((u + 0x7FFFu + ((u >> 16) & 1u)) >> 16);
}
__device__ __forceinline__ float b2f(u16 h) { return __uint_as_float(((u32)h) << 16); }
__device__ __forceinline__ u32 encf(float f) {             // order-preserving f32->u32
  u32 u = __float_as_uint(f);
  return (u & 0x80000000u) ? ~u : (u | 0x80000000u);
}
__device__ __forceinline__ float decf(u32 e) {
  return __uint_as_float((e & 0x80000000u) ? (e & 0x7FFFFFFFu) : ~e);
}
__device__ __forceinline__ float mish_f(float v) {
  if (v > 15.f) return v;
  float ev = __expf(v);
  float p = ev * (ev + 2.f);
  return v * p / (p + 2.f);
}
__device__ __forceinline__ float ldf(const void* p, int i, int bf) {
  return bf ? b2f(((const u16*)p)[i]) : ((const float*)p)[i];
}
__device__ __forceinline__ u8t f2fp8(float f) {            // f32 -> fp8 e4m3 (OCP)
  return (u8t)(__builtin_amdgcn_cvt_pk_fp8_f32(f, f, 0, 0) & 0xFF);
}
// fp8 LDS tile [96][256]: row stride 256B, XOR swizzle bits 4..6 (2-way banks = free)
__device__ __forceinline__ char* tp8(char* base, int row, int colb) {
  return base + ((row << 8) + (colb ^ ((row & 7) << 4)));
}

// ---------------- dtype detector ----------------
__global__ void detect_dtype_kernel(const void* __restrict__ x, int* __restrict__ flag) {
  __shared__ int cnt;
  const int tid = threadIdx.x;
  if (tid == 0) cnt = 0;
  __syncthreads();
  const u16* p = (const u16*)x;
  u16 h = p[tid * 96 + 4];
  int e = (int)((h >> 7) & 0xFF);
  if (e >= 116 && e <= 134) atomicAdd(&cnt, 1);
  __syncthreads();
  if (tid == 0) *flag = (cnt >= 128) ? 1 : 0;
}

// ---------------- prep kernels ----------------
// W_embed[k][n] -> fp8 MFMA-fragment tiles: dst[(nt*8+kt)*512 + lane*8 + e],
// lane = lg*16+lr covers B[n=nt*16+lr][k=kt*32+lg*8+e]. grid 256(k), 256 thr(n).
__global__ void prep_wemb8(const void* __restrict__ W, u8t* __restrict__ Wt8,
                           const int* __restrict__ flag) {
  const int k = blockIdx.x, n = threadIdx.x;
  const int bf = *flag;
  u8t v = f2fp8(ldf(W, (k << 8) + n, bf));
  int nt = n >> 4, lr = n & 15, kt = k >> 5, lg = (k >> 3) & 3, e = k & 7;
  Wt8[(((nt << 3) + kt) << 9) + (((lg << 4) + lr) << 3) + e] = v;
}

// Wqk8 tiled fp8: (Wq @ Wk^T)[k][n]. grid 256 (n), 256 thr (k).
__global__ void prep_wqk8(const void* __restrict__ Wq, const void* __restrict__ Wk,
                          u8t* __restrict__ Wqk8, const int* __restrict__ flag) {
  __shared__ float wkrow[256];
  __shared__ u16 wqt[64][260];
  const int bf = *flag;
  const int n = blockIdx.x, k = threadIdx.x;
  wkrow[k] = ldf(Wk, (n << 8) + k, bf);
  float s = 0.f;
  for (int d0 = 0; d0 < 256; d0 += 64) {
    __syncthreads();
    for (int it = 0; it < 64; ++it) {
      int kk = (it << 2) + (threadIdx.x >> 6);
      int dd = threadIdx.x & 63;
      wqt[dd][kk] = f2b(ldf(Wq, (kk << 8) + d0 + dd, bf));
    }
    __syncthreads();
    #pragma unroll 8
    for (int dd = 0; dd < 64; ++dd) s += b2f(wqt[dd][k]) * wkrow[d0 + dd];
  }
  int nt = n >> 4, lr = n & 15, kt = k >> 5, lg = (k >> 3) & 3, e = k & 7;
  Wqk8[(((nt << 3) + kt) << 9) + (((lg << 4) + lr) << 3) + e] = f2fp8(s);
}

// dqkp8[q][d]=fp8(sum_n Wk[d][n]*dq[q][n]); u8v=fp8(Wq@bk); w8v=fp8(Wk@bq);
// dqc[q]=dq_q.bk, dqc[7]=bq.bk. grid 9, 256 thr.
__global__ void prep_vec8(const void* __restrict__ Wq, const void* __restrict__ Wk,
                          const void* __restrict__ bq, const void* __restrict__ bk,
                          const void* __restrict__ dq,
                          u8t* __restrict__ dqkp8, u8t* __restrict__ u8v,
                          u8t* __restrict__ w8v, float* __restrict__ dqc,
                          const int* __restrict__ flag) {
  const int bf = *flag;
  const int blk = blockIdx.x, d = threadIdx.x;
  if (blk < 7) {
    float s = 0.f;
    for (int nn = 0; nn < 256; ++nn)
      s += ldf(Wk, (d << 8) + nn, bf) * ldf(dq, (blk << 8) + nn, bf);
    dqkp8[(blk << 8) + d] = f2fp8(s);
  } else if (blk == 7) {
    float su = 0.f, sw = 0.f;
    for (int nn = 0; nn < 256; ++nn) {
      su += ldf(Wq, (d << 8) + nn, bf) * ldf(bk, nn, bf);
      sw += ldf(Wk, (d << 8) + nn, bf) * ldf(bq, nn, bf);
    }
    u8v[d] = f2fp8(su); w8v[d] = f2fp8(sw);
  } else {
    if (d < 7) {
      float s = 0.f;
      for (int nn = 0; nn < 256; ++nn) s += ldf(dq, (d << 8) + nn, bf) * ldf(bk, nn, bf);
      dqc[d] = s;
    } else if (d == 7) {
      float s = 0.f;
      for (int nn = 0; nn < 256; ++nn) s += ldf(bq, nn, bf) * ldf(bk, nn, bf);
      dqc[7] = s;
    }
  }
}

// packed inverse table in ONE block (init + scatter, deterministic)
__global__ void prep_invP(const int* __restrict__ vi, const int* __restrict__ pi,
                          const int* __restrict__ qi, const int* __restrict__ qpi,
                          int nv, int np, u32* __restrict__ invP) {
  const int tid = threadIdx.x;   // 256
  for (int i = tid; i < 6561; i += 256) invP[i] = 0u;
  __syncthreads();
  for (int i = tid; i < nv; i += 256) atomicOr(&invP[vi[i]], (u32)(pi[i] + 1));
  for (int i = tid; i < np; i += 256) atomicOr(&invP[qi[i]], ((u32)(qpi[i] + 1)) << 16);
}

// ---------------- persistent fused kernel (fp8, 2 blocks/CU) ----------------
// LDS: bufA [96][256] fp8 swz (x -> T; rows 81..89 = dqkp,u,w consts) @     0 (24576)
//      bufP [96][256] fp8 swz (pe)                                   @ 24576 (24576)
//      pol  [2187] u32                                               @ 49152 ( 8752)
//      alpha[96] f32 @57904, beta[96] f32 @58288, dqcS[8] @58672
#define LDS_TOTAL 58704

__global__ __launch_bounds__(512, 4)
void dirpolicy_fp8(const void* __restrict__ x,
                   const void* __restrict__ b_embed,
                   const u8t* __restrict__ Wt8,
                   const u8t* __restrict__ Wqk8,
                   const u8t* __restrict__ dqkp8,
                   const u8t* __restrict__ u8v,
                   const u8t* __restrict__ w8v,
                   const float* __restrict__ dqc,
                   const u32* __restrict__ invP,
                   void* __restrict__ out,
                   const int* __restrict__ dflag,
                   int Btot) {
  extern __shared__ char smem[];
  char* bufA = smem;
  char* bufP = smem + 24576;
  u32* pol = (u32*)(smem + 49152);
  float* alpha = (float*)(smem + 57904);
  float* beta  = (float*)(smem + 58288);
  float* dqcS  = (float*)(smem + 58672);

  const int tid = threadIdx.x;
  const int lane = tid & 63;
  const int w = tid >> 6;
  const int lr = lane & 15;
  const int lg = lane >> 4;
  const int isbf = *dflag;
  const u32 ENEG = encf(-1e10f);
  const int wr = w >> 2, wc = w & 3;          // phases 1/3: 2x4 wave grid
  const int wr4 = (w >= 3) ? 1 : 0;           // phase 4: 2x3 wave grid (w<6)
  const int wc4 = w - wr4 * 3;

  // ---- prologue (once per block) ----
  for (int i = tid; i < 2304; i += 512) {     // const rows 81..89 of bufA
    int q = i >> 8, d = i & 255;
    u8t bv = (q < 7) ? dqkp8[i] : ((q == 7) ? u8v[d] : w8v[d]);
    *tp8(bufA, 81 + q, d) = bv;
  }
  for (int i = tid; i < 2187; i += 512) pol[i] = ENEG;
  if (tid < 8) dqcS[tid] = dqc[tid];
  float biasv[4];
  #pragma unroll
  for (int j = 0; j < 4; ++j) biasv[j] = ldf(b_embed, (wc << 6) + j * 16 + lr, isbf);

  // ---- persistent element loop ----
  for (int b = blockIdx.x; b < Btot; b += (int)gridDim.x) {
    // ===== stage x -> bufA rows 0..80 (fp8) =====
    if (isbf) {
      const u16* xb = (const u16*)x + (size_t)b * 20736u;
      #pragma unroll
      for (int c = 0; c < 6; ++c) {
        int idx = tid + (c << 9);
        if (idx < 2592) {
          bfrag v = *(const bfrag*)(xb + (idx << 3));
          u32 lo = __builtin_amdgcn_cvt_pk_fp8_f32(b2f((u16)v[0]), b2f((u16)v[1]), 0, 0);
          lo = __builtin_amdgcn_cvt_pk_fp8_f32(b2f((u16)v[2]), b2f((u16)v[3]), lo, 1);
          u32 hi = __builtin_amdgcn_cvt_pk_fp8_f32(b2f((u16)v[4]), b2f((u16)v[5]), 0, 0);
          hi = __builtin_amdgcn_cvt_pk_fp8_f32(b2f((u16)v[6]), b2f((u16)v[7]), hi, 1);
          uint2 pk; pk.x = lo; pk.y = hi;
          int row = idx >> 5, colb = (idx & 31) << 3;
          *(uint2*)tp8(bufA, row, colb) = pk;
        }
      }
    } else {
      const float4* xs = (const float4*)((const float*)x + (size_t)b * 20736u);
      #pragma unroll
      for (int c = 0; c < 6; ++c) {
        int idx = tid + (c << 9);
        if (idx < 2592) {
          float4 p0 = xs[idx * 2], p1 = xs[idx * 2 + 1];
          u32 lo = __builtin_amdgcn_cvt_pk_fp8_f32(p0.x, p0.y, 0, 0);
          lo = __builtin_amdgcn_cvt_pk_fp8_f32(p0.z, p0.w, lo, 1);
          u32 hi = __builtin_amdgcn_cvt_pk_fp8_f32(p1.x, p1.y, 0, 0);
          hi = __builtin_amdgcn_cvt_pk_fp8_f32(p1.z, p1.w, hi, 1);
          uint2 pk; pk.x = lo; pk.y = hi;
          int row = idx >> 5, colb = (idx & 31) << 3;
          *(uint2*)tp8(bufA, row, colb) = pk;
        }
      }
    }
    __syncthreads();   // bar0: x staged, pol (re)inited

    // ===== phase 1: pe = mish(x @ We + b) -> bufP (fp8) =====
    {
      facc acc[3][4];
      facc z4 = {0.f, 0.f, 0.f, 0.f};
      #pragma unroll
      for (int i = 0; i < 3; ++i)
        #pragma unroll
        for (int j = 0; j < 4; ++j) acc[i][j] = z4;
      #pragma unroll
      for (int kt = 0; kt < 8; ++kt) {
        long bb[4], a[3];
        #pragma unroll
        for (int j = 0; j < 4; ++j)
          bb[j] = *(const long*)(Wt8 + (((((wc << 2) + j) << 3) + kt) << 9) + (lane << 3));
        #pragma unroll
        for (int i = 0; i < 3; ++i)
          a[i] = *(const long*)tp8(bufA, wr * 48 + i * 16 + lr, (kt << 5) + (lg << 3));
        #pragma unroll
        for (int i = 0; i < 3; ++i)
          #pragma unroll
          for (int j = 0; j < 4; ++j)
            acc[i][j] = __builtin_amdgcn_mfma_f32_16x16x32_fp8_fp8(a[i], bb[j], acc[i][j], 0, 0, 0);
      }
      #pragma unroll
      for (int j = 0; j < 4; ++j) {
        const int col = (wc << 6) + j * 16 + lr;
        #pragma unroll
        for (int i = 0; i < 3; ++i)
          #pragma unroll
          for (int r = 0; r < 4; ++r) {
            const int row = wr * 48 + i * 16 + (lg << 2) + r;
            if (row < 81)
              *tp8(bufP, row, col) = f2fp8(mish_f(acc[i][j][r] + biasv[j]));
          }
      }
    }
    __syncthreads();   // bar1: pe visible; x reads done (T may overwrite bufA)

    // ===== phase 3: T = pe @ Wqk -> bufA rows 0..80 (fp8) =====
    {
      facc acc2[3][4];
      facc z4 = {0.f, 0.f, 0.f, 0.f};
      #pragma unroll
      for (int i = 0; i < 3; ++i)
        #pragma unroll
        for (int j = 0; j < 4; ++j) acc2[i][j] = z4;
      #pragma unroll
      for (int kt = 0; kt < 8; ++kt) {
        long bb[4], a[3];
        #pragma unroll
        for (int j = 0; j < 4; ++j)
          bb[j] = *(const long*)(Wqk8 + (((((wc << 2) + j) << 3) + kt) << 9) + (lane << 3));
        #pragma unroll
        for (int i = 0; i < 3; ++i)
          a[i] = *(const long*)tp8(bufP, wr * 48 + i * 16 + lr, (kt << 5) + (lg << 3));
        #pragma unroll
        for (int i = 0; i < 3; ++i)
          #pragma unroll
          for (int j = 0; j < 4; ++j)
            acc2[i][j] = __builtin_amdgcn_mfma_f32_16x16x32_fp8_fp8(a[i], bb[j], acc2[i][j], 0, 0, 0);
      }
      #pragma unroll
      for (int j = 0; j < 4; ++j) {
        const int col = (wc << 6) + j * 16 + lr;
        #pragma unroll
        for (int i = 0; i < 3; ++i)
          #pragma unroll
          for (int r = 0; r < 4; ++r) {
            const int row = wr * 48 + i * 16 + (lg << 2) + r;
            if (row < 81) *tp8(bufA, row, col) = f2fp8(acc2[i][j][r]);
          }
      }
    }
    __syncthreads();   // bar2: T visible

    // issue invP loads early (hidden under phase-4 MFMA)
    u32 ivr[3][2][4];
    if (w < 6) {
      #pragma unroll
      for (int i = 0; i < 3; ++i)
        #pragma unroll
        for (int j = 0; j < 2; ++j)
          #pragma unroll
          for (int r = 0; r < 4; ++r) {
            int rowb = wr4 * 48 + i * 16 + (lg << 2) + r;
            int colb = wc4 * 32 + j * 16 + lr;
            ivr[i][j][r] = (rowb < 81 && colb < 81) ? invP[rowb * 81 + colb] : 0u;
          }
    }

    // ===== phase 4: board = [T;dqkp;u;w] @ pe^T (waves 0..5) =====
    facc bd[3][2];
    {
      facc z4 = {0.f, 0.f, 0.f, 0.f};
      #pragma unroll
      for (int i = 0; i < 3; ++i)
        #pragma unroll
        for (int j = 0; j < 2; ++j) bd[i][j] = z4;
    }
    if (w < 6) {
      #pragma unroll
      for (int kt = 0; kt < 8; ++kt) {
        long a[3], bb[2];
        #pragma unroll
        for (int i = 0; i < 3; ++i)
          a[i] = *(const long*)tp8(bufA, wr4 * 48 + i * 16 + lr, (kt << 5) + (lg << 3));
        #pragma unroll
        for (int j = 0; j < 2; ++j)
          bb[j] = *(const long*)tp8(bufP, wc4 * 32 + j * 16 + lr, (kt << 5) + (lg << 3));
        #pragma unroll
        for (int i = 0; i < 3; ++i)
          #pragma unroll
          for (int j = 0; j < 2; ++j)
            bd[i][j] = __builtin_amdgcn_mfma_f32_16x16x32_fp8_fp8(a[i], bb[j], bd[i][j], 0, 0, 0);
      }
      // rows 88/89 (u,w) -> alpha/beta (writers: wr4==1, i==2, lg==2, r=0/1)
      if (wr4 == 1 && lg == 2) {
        const float c7 = dqcS[7];
        #pragma unroll
        for (int j = 0; j < 2; ++j) {
          const int colb = wc4 * 32 + j * 16 + lr;
          alpha[colb] = (bd[2][j][0] + c7) * 0.0625f;
          beta[colb]  = bd[2][j][1] * 0.0625f;
        }
      }
    }
    __syncthreads();   // bar3: alpha/beta visible

    // ===== scatter-max from accumulators =====
    if (w < 6) {
      float betv[2];
      #pragma unroll
      for (int j = 0; j < 2; ++j) {
        int colb = wc4 * 32 + j * 16 + lr;
        betv[j] = (colb < 81) ? beta[colb] : 0.f;
      }
      #pragma unroll
      for (int i = 0; i < 3; ++i)
        #pragma unroll
        for (int r = 0; r < 4; ++r) {
          const int rowb = wr4 * 48 + i * 16 + (lg << 2) + r;
          if (rowb < 81) {
            const float av = alpha[rowb];
            #pragma unroll
            for (int j = 0; j < 2; ++j) {
              const int colb = wc4 * 32 + j * 16 + lr;
              if (colb < 81) {
                const u32 ev = encf(bd[i][j][r] * 0.0625f + av + betv[j]);
                const u32 pv = ivr[i][j][r];
                if (pv & 0xFFFFu) atomicMax(&pol[(pv & 0xFFFFu) - 1], ev);
                if (pv >> 16)     atomicMax(&pol[(pv >> 16) - 1], ev);
              }
            }
          } else if (rowb < 88) {
            const float dv = dqcS[rowb - 81];
            #pragma unroll
            for (int j = 0; j < 2; ++j) {
              const int colb = wc4 * 32 + j * 16 + lr;
              if (colb < 81)
                pol[1620 + (rowb - 81) * 81 + colb] = encf((bd[i][j][r] + dv) * 0.0625f);
            }
          }
        }
    }
    __syncthreads();   // bar4: pol complete

    // ===== decode + store + re-init pol =====
    if (isbf) {
      u16* ob = (u16*)out + (size_t)b * 2187u;
      for (int p2 = tid; p2 < 2187; p2 += 512) {
        u32 v = pol[p2]; pol[p2] = ENEG;
        ob[p2] = f2b(decf(v));
      }
    } else {
      float* ob = (float*)out + (size_t)b * 2187u;
      for (int p2 = tid; p2 < 2187; p2 += 512) {
        u32 v = pol[p2]; pol[p2] = ENEG;
        ob[p2] = decf(v);
      }
    }
  }
}

// ---------------- launcher ----------------
extern "C" void kernel_launch(void* const* d_in, const int* in_sizes, int n_in,
                              void* d_out, int out_size, void* d_ws, size_t ws_size,
                              hipStream_t stream) {
  const void* x        = d_in[0];
  const void* W_embed  = d_in[1];
  const void* b_embed  = d_in[2];
  const void* Wq       = d_in[3];
  const void* bq       = d_in[4];
  const void* Wk       = d_in[5];
  const void* bk_      = d_in[6];
  const void* dq       = d_in[7];
  const int* valid_idx         = (const int*)d_in[8];
  const int* policy_idx        = (const int*)d_in[9];
  const int* promo_idx         = (const int*)d_in[10];
  const int* promo_policy_idx  = (const int*)d_in[11];
  const int n_valid = in_sizes[8];
  const int n_promo = in_sizes[10];
  const int B = in_sizes[0] / 20736;   // 81*256

  // ws layout
  char* ws = (char*)d_ws;
  u8t* Wt8    = (u8t*)(ws);               // 65536
  u8t* Wqk8   = (u8t*)(ws + 65536);       // 65536
  u8t* dqkp8  = (u8t*)(ws + 131072);      // 1792 (+pad)
  u8t* u8v    = (u8t*)(ws + 133120);      // 256
  u8t* w8v    = (u8t*)(ws + 133376);      // 256
  float* dqc  = (float*)(ws + 133632);    // 32
  int* dflag  = (int*)(ws + 133664);      // 32
  u32* invP   = (u32*)(ws + 133696);      // 26244
  if (ws_size < 160000) return;

  detect_dtype_kernel<<<dim3(1), dim3(256), 0, stream>>>(x, dflag);
  prep_wemb8<<<dim3(256), dim3(256), 0, stream>>>(W_embed, Wt8, dflag);
  prep_wqk8<<<dim3(256), dim3(256), 0, stream>>>(Wq, Wk, Wqk8, dflag);
  prep_vec8<<<dim3(9), dim3(256), 0, stream>>>(Wq, Wk, bq, bk_, dq,
                                               dqkp8, u8v, w8v, dqc, dflag);
  prep_invP<<<dim3(1), dim3(256), 0, stream>>>(
      valid_idx, policy_idx, promo_idx, promo_policy_idx, n_valid, n_promo, invP);

  (void)hipFuncSetAttribute((const void*)dirpolicy_fp8,
                            hipFuncAttributeMaxDynamicSharedMemorySize, LDS_TOTAL);
  int grid = (B < 512) ? B : 512;
  if (grid > 0)
    dirpolicy_fp8<<<dim3(grid), dim3(512), LDS_TOTAL, stream>>>(
        x, b_embed, Wt8, Wqk8, dqkp8, u8v, w8v, dqc, invP, d_out, dflag, B);
}

// Round 6
// 490.490 us; speedup vs baseline: 2.4819x; 2.4819x over previous
//
#include <hip/hip_runtime.h>

typedef unsigned short u16;
typedef unsigned int u32;
typedef unsigned char u8t;
using bfrag = __attribute__((ext_vector_type(8))) short;   // 8 x bf16 (raw bits)
using facc  = __attribute__((ext_vector_type(4))) float;   // MFMA accumulator

// ---------------- numeric helpers ----------------
__device__ __forceinline__ u16 f2b(float f) {              // f32 -> bf16 (RNE)
  u32 u = __float_as_uint(f);
  return (u16)((u + 0x7FFFu + ((u >> 16) & 1u)) >> 16);
}
__device__ __forceinline__ float b2f(u16 h) { return __uint_as_float(((u32)h) << 16); }
__device__ __forceinline__ u32 encf(float f) {             // order-preserving f32->u32
  u32 u = __float_as_uint(f);
  return (u & 0x80000000u) ? ~u : (u | 0x80000000u);
}
__device__ __forceinline__ float decf(u32 e) {
  return __uint_as_float((e & 0x80000000u) ? (e & 0x7FFFFFFFu) : ~e);
}
__device__ __forceinline__ float mish_f(float v) {
  if (v > 15.f) return v;
  float ev = __expf(v);
  float p = ev * (ev + 2.f);
  return v * p / (p + 2.f);
}
__device__ __forceinline__ float ldf(const void* p, int i, int bf) {
  return bf ? b2f(((const u16*)p)[i]) : ((const float*)p)[i];
}
__device__ __forceinline__ u8t f2fp8(float f) {            // f32 -> fp8 e4m3 (OCP)
  return (u8t)(__builtin_amdgcn_cvt_pk_fp8_f32(f, f, 0, 0) & 0xFF);
}
// fp8 LDS tile [96][256]: row stride 256B, XOR swizzle bits 4..6
__device__ __forceinline__ char* tp8(char* base, int row, int colb) {
  return base + ((row << 8) + (colb ^ ((row & 7) << 4)));
}

// ---------------- dtype detector ----------------
__global__ void detect_dtype_kernel(const void* __restrict__ x, int* __restrict__ flag) {
  __shared__ int cnt;
  const int tid = threadIdx.x;
  if (tid == 0) cnt = 0;
  __syncthreads();
  const u16* p = (const u16*)x;
  u16 h = p[tid * 96 + 4];
  int e = (int)((h >> 7) & 0xFF);
  if (e >= 116 && e <= 134) atomicAdd(&cnt, 1);
  __syncthreads();
  if (tid == 0) *flag = (cnt >= 128) ? 1 : 0;
}

// ---------------- prep kernels ----------------
// W_embed[k][n] -> fp8 MFMA-fragment tiles: dst[(nt*8+kt)*512 + lane*8 + e],
// lane = lg*16+lr covers B[n=nt*16+lr][k=kt*32+lg*8+e]. grid 256(k), 256 thr(n).
__global__ void prep_wemb8(const void* __restrict__ W, u8t* __restrict__ Wt8,
                           const int* __restrict__ flag) {
  const int k = blockIdx.x, n = threadIdx.x;
  const int bf = *flag;
  u8t v = f2fp8(ldf(W, (k << 8) + n, bf));
  int nt = n >> 4, lr = n & 15, kt = k >> 5, lg = (k >> 3) & 3, e = k & 7;
  Wt8[(((nt << 3) + kt) << 9) + (((lg << 4) + lr) << 3) + e] = v;
}

// Wqk8 tiled fp8: (Wq @ Wk^T)[k][n]. grid 256 (n), 256 thr (k).
__global__ void prep_wqk8(const void* __restrict__ Wq, const void* __restrict__ Wk,
                          u8t* __restrict__ Wqk8, const int* __restrict__ flag) {
  __shared__ float wkrow[256];
  __shared__ u16 wqt[64][260];
  const int bf = *flag;
  const int n = blockIdx.x, k = threadIdx.x;
  wkrow[k] = ldf(Wk, (n << 8) + k, bf);
  float s = 0.f;
  for (int d0 = 0; d0 < 256; d0 += 64) {
    __syncthreads();
    for (int it = 0; it < 64; ++it) {
      int kk = (it << 2) + (threadIdx.x >> 6);
      int dd = threadIdx.x & 63;
      wqt[dd][kk] = f2b(ldf(Wq, (kk << 8) + d0 + dd, bf));
    }
    __syncthreads();
    #pragma unroll 8
    for (int dd = 0; dd < 64; ++dd) s += b2f(wqt[dd][k]) * wkrow[d0 + dd];
  }
  int nt = n >> 4, lr = n & 15, kt = k >> 5, lg = (k >> 3) & 3, e = k & 7;
  Wqk8[(((nt << 3) + kt) << 9) + (((lg << 4) + lr) << 3) + e] = f2fp8(s);
}

// dqkp8[q][d]=fp8(sum_n Wk[d][n]*dq[q][n]); u8v=fp8(Wq@bk); w8v=fp8(Wk@bq);
// dqc[q]=dq_q.bk, dqc[7]=bq.bk. grid 9, 256 thr.
__global__ void prep_vec8(const void* __restrict__ Wq, const void* __restrict__ Wk,
                          const void* __restrict__ bq, const void* __restrict__ bk,
                          const void* __restrict__ dq,
                          u8t* __restrict__ dqkp8, u8t* __restrict__ u8v,
                          u8t* __restrict__ w8v, float* __restrict__ dqc,
                          const int* __restrict__ flag) {
  const int bf = *flag;
  const int blk = blockIdx.x, d = threadIdx.x;
  if (blk < 7) {
    float s = 0.f;
    for (int nn = 0; nn < 256; ++nn)
      s += ldf(Wk, (d << 8) + nn, bf) * ldf(dq, (blk << 8) + nn, bf);
    dqkp8[(blk << 8) + d] = f2fp8(s);
  } else if (blk == 7) {
    float su = 0.f, sw = 0.f;
    for (int nn = 0; nn < 256; ++nn) {
      su += ldf(Wq, (d << 8) + nn, bf) * ldf(bk, nn, bf);
      sw += ldf(Wk, (d << 8) + nn, bf) * ldf(bq, nn, bf);
    }
    u8v[d] = f2fp8(su); w8v[d] = f2fp8(sw);
  } else {
    if (d < 7) {
      float s = 0.f;
      for (int nn = 0; nn < 256; ++nn) s += ldf(dq, (d << 8) + nn, bf) * ldf(bk, nn, bf);
      dqc[d] = s;
    } else if (d == 7) {
      float s = 0.f;
      for (int nn = 0; nn < 256; ++nn) s += ldf(bq, nn, bf) * ldf(bk, nn, bf);
      dqc[7] = s;
    }
  }
}

// packed inverse table in ONE block (init + scatter, deterministic)
__global__ void prep_invP(const int* __restrict__ vi, const int* __restrict__ pi,
                          const int* __restrict__ qi, const int* __restrict__ qpi,
                          int nv, int np, u32* __restrict__ invP) {
  const int tid = threadIdx.x;   // 256
  for (int i = tid; i < 6561; i += 256) invP[i] = 0u;
  __syncthreads();
  for (int i = tid; i < nv; i += 256) atomicOr(&invP[vi[i]], (u32)(pi[i] + 1));
  for (int i = tid; i < np; i += 256) atomicOr(&invP[qi[i]], ((u32)(qpi[i] + 1)) << 16);
}

// ---------------- fused kernel (fp8, one element per block, 2 blocks/CU) ----------------
// LDS: bufA [96][256] fp8 swz (x -> T; rows 81..89 = dqkp,u,w consts) @     0 (24576)
//      bufP [96][256] fp8 swz (pe)                                   @ 24576 (24576)
//      pol  [2187] u32                                               @ 49152 ( 8752)
//      alpha[96] f32 @57904, beta[96] f32 @58288, dqcS[8] @58672
#define LDS_TOTAL 58704

// NOTE: hipcc treats the 2nd launch_bounds arg CUDA-style (min BLOCKS/CU):
// (512,2) -> 2 blk * 8 waves / 4 SIMD = 4 waves/SIMD -> 128-VGPR cap (r3: 124, no spill).
// (512,4) in r5 capped at 64 VGPR and spilled ~1.3GB to scratch. Keep (512,2).
__global__ __launch_bounds__(512, 2)
void dirpolicy_fp8(const void* __restrict__ x,
                   const void* __restrict__ b_embed,
                   const u8t* __restrict__ Wt8,
                   const u8t* __restrict__ Wqk8,
                   const u8t* __restrict__ dqkp8,
                   const u8t* __restrict__ u8v,
                   const u8t* __restrict__ w8v,
                   const float* __restrict__ dqc,
                   const u32* __restrict__ invP,
                   void* __restrict__ out,
                   const int* __restrict__ dflag) {
  extern __shared__ char smem[];
  char* bufA = smem;
  char* bufP = smem + 24576;
  u32* pol = (u32*)(smem + 49152);
  float* alpha = (float*)(smem + 57904);
  float* beta  = (float*)(smem + 58288);
  float* dqcS  = (float*)(smem + 58672);

  const int tid = threadIdx.x;
  const int lane = tid & 63;
  const int w = tid >> 6;
  const int lr = lane & 15;
  const int lg = lane >> 4;
  const int isbf = *dflag;
  const int b = blockIdx.x;
  const u32 ENEG = encf(-1e10f);
  const int wr = w >> 2, wc = w & 3;          // phases 1/3: 2x4 wave grid
  const int wr4 = (w >= 3) ? 1 : 0;           // phase 4: 2x3 wave grid (w<6)
  const int wc4 = w - wr4 * 3;

  // ---- prologue: consts + pol init ----
  for (int i = tid; i < 2304; i += 512) {     // const rows 81..89 of bufA
    int q = i >> 8, d = i & 255;
    u8t bv = (q < 7) ? dqkp8[i] : ((q == 7) ? u8v[d] : w8v[d]);
    *tp8(bufA, 81 + q, d) = bv;
  }
  for (int i = tid; i < 2187; i += 512) pol[i] = ENEG;
  if (tid < 8) dqcS[tid] = dqc[tid];
  float biasv[4];
  #pragma unroll
  for (int j = 0; j < 4; ++j) biasv[j] = ldf(b_embed, (wc << 6) + j * 16 + lr, isbf);

  // ===== stage x -> bufA rows 0..80 (fp8) =====
  if (isbf) {
    const u16* xb = (const u16*)x + (size_t)b * 20736u;
    #pragma unroll
    for (int c = 0; c < 6; ++c) {
      int idx = tid + (c << 9);
      if (idx < 2592) {
        bfrag v = *(const bfrag*)(xb + (idx << 3));
        u32 lo = __builtin_amdgcn_cvt_pk_fp8_f32(b2f((u16)v[0]), b2f((u16)v[1]), 0, 0);
        lo = __builtin_amdgcn_cvt_pk_fp8_f32(b2f((u16)v[2]), b2f((u16)v[3]), lo, 1);
        u32 hi = __builtin_amdgcn_cvt_pk_fp8_f32(b2f((u16)v[4]), b2f((u16)v[5]), 0, 0);
        hi = __builtin_amdgcn_cvt_pk_fp8_f32(b2f((u16)v[6]), b2f((u16)v[7]), hi, 1);
        uint2 pk; pk.x = lo; pk.y = hi;
        int row = idx >> 5, colb = (idx & 31) << 3;
        *(uint2*)tp8(bufA, row, colb) = pk;
      }
    }
  } else {
    const float4* xs = (const float4*)((const float*)x + (size_t)b * 20736u);
    #pragma unroll
    for (int c = 0; c < 6; ++c) {
      int idx = tid + (c << 9);
      if (idx < 2592) {
        float4 p0 = xs[idx * 2], p1 = xs[idx * 2 + 1];
        u32 lo = __builtin_amdgcn_cvt_pk_fp8_f32(p0.x, p0.y, 0, 0);
        lo = __builtin_amdgcn_cvt_pk_fp8_f32(p0.z, p0.w, lo, 1);
        u32 hi = __builtin_amdgcn_cvt_pk_fp8_f32(p1.x, p1.y, 0, 0);
        hi = __builtin_amdgcn_cvt_pk_fp8_f32(p1.z, p1.w, hi, 1);
        uint2 pk; pk.x = lo; pk.y = hi;
        int row = idx >> 5, colb = (idx & 31) << 3;
        *(uint2*)tp8(bufA, row, colb) = pk;
      }
    }
  }
  __syncthreads();   // bar0: x staged, consts + pol visible

  // ===== phase 1: pe = mish(x @ We + b) -> bufP (fp8) =====
  {
    facc acc[3][4];
    facc z4 = {0.f, 0.f, 0.f, 0.f};
    #pragma unroll
    for (int i = 0; i < 3; ++i)
      #pragma unroll
      for (int j = 0; j < 4; ++j) acc[i][j] = z4;
    #pragma unroll
    for (int kt = 0; kt < 8; ++kt) {
      long bb[4], a[3];
      #pragma unroll
      for (int j = 0; j < 4; ++j)
        bb[j] = *(const long*)(Wt8 + (((((wc << 2) + j) << 3) + kt) << 9) + (lane << 3));
      #pragma unroll
      for (int i = 0; i < 3; ++i)
        a[i] = *(const long*)tp8(bufA, wr * 48 + i * 16 + lr, (kt << 5) + (lg << 3));
      #pragma unroll
      for (int i = 0; i < 3; ++i)
        #pragma unroll
        for (int j = 0; j < 4; ++j)
          acc[i][j] = __builtin_amdgcn_mfma_f32_16x16x32_fp8_fp8(a[i], bb[j], acc[i][j], 0, 0, 0);
    }
    #pragma unroll
    for (int j = 0; j < 4; ++j) {
      const int col = (wc << 6) + j * 16 + lr;
      #pragma unroll
      for (int i = 0; i < 3; ++i)
        #pragma unroll
        for (int r = 0; r < 4; ++r) {
          const int row = wr * 48 + i * 16 + (lg << 2) + r;
          if (row < 81)
            *tp8(bufP, row, col) = f2fp8(mish_f(acc[i][j][r] + biasv[j]));
        }
    }
  }
  __syncthreads();   // bar1: pe visible; x reads done (T may overwrite bufA)

  // ===== phase 3: T = pe @ Wqk -> bufA rows 0..80 (fp8) =====
  {
    facc acc2[3][4];
    facc z4 = {0.f, 0.f, 0.f, 0.f};
    #pragma unroll
    for (int i = 0; i < 3; ++i)
      #pragma unroll
      for (int j = 0; j < 4; ++j) acc2[i][j] = z4;
    #pragma unroll
    for (int kt = 0; kt < 8; ++kt) {
      long bb[4], a[3];
      #pragma unroll
      for (int j = 0; j < 4; ++j)
        bb[j] = *(const long*)(Wqk8 + (((((wc << 2) + j) << 3) + kt) << 9) + (lane << 3));
      #pragma unroll
      for (int i = 0; i < 3; ++i)
        a[i] = *(const long*)tp8(bufP, wr * 48 + i * 16 + lr, (kt << 5) + (lg << 3));
      #pragma unroll
      for (int i = 0; i < 3; ++i)
        #pragma unroll
        for (int j = 0; j < 4; ++j)
          acc2[i][j] = __builtin_amdgcn_mfma_f32_16x16x32_fp8_fp8(a[i], bb[j], acc2[i][j], 0, 0, 0);
    }
    #pragma unroll
    for (int j = 0; j < 4; ++j) {
      const int col = (wc << 6) + j * 16 + lr;
      #pragma unroll
      for (int i = 0; i < 3; ++i)
        #pragma unroll
        for (int r = 0; r < 4; ++r) {
          const int row = wr * 48 + i * 16 + (lg << 2) + r;
          if (row < 81) *tp8(bufA, row, col) = f2fp8(acc2[i][j][r]);
        }
    }
  }
  __syncthreads();   // bar2: T visible

  // ===== phase 4: board = [T;dqkp;u;w] @ pe^T (waves 0..5) =====
  facc bd[3][2];
  {
    facc z4 = {0.f, 0.f, 0.f, 0.f};
    #pragma unroll
    for (int i = 0; i < 3; ++i)
      #pragma unroll
      for (int j = 0; j < 2; ++j) bd[i][j] = z4;
  }
  if (w < 6) {
    #pragma unroll
    for (int kt = 0; kt < 8; ++kt) {
      long a[3], bb[2];
      #pragma unroll
      for (int i = 0; i < 3; ++i)
        a[i] = *(const long*)tp8(bufA, wr4 * 48 + i * 16 + lr, (kt << 5) + (lg << 3));
      #pragma unroll
      for (int j = 0; j < 2; ++j)
        bb[j] = *(const long*)tp8(bufP, wc4 * 32 + j * 16 + lr, (kt << 5) + (lg << 3));
      #pragma unroll
      for (int i = 0; i < 3; ++i)
        #pragma unroll
        for (int j = 0; j < 2; ++j)
          bd[i][j] = __builtin_amdgcn_mfma_f32_16x16x32_fp8_fp8(a[i], bb[j], bd[i][j], 0, 0, 0);
    }
    // rows 88/89 (u,w) -> alpha/beta (writers: wr4==1, i==2, lg==2, r=0/1)
    if (wr4 == 1 && lg == 2) {
      const float c7 = dqcS[7];
      #pragma unroll
      for (int j = 0; j < 2; ++j) {
        const int colb = wc4 * 32 + j * 16 + lr;
        alpha[colb] = (bd[2][j][0] + c7) * 0.0625f;
        beta[colb]  = bd[2][j][1] * 0.0625f;
      }
    }
  }
  __syncthreads();   // bar3: alpha/beta visible

  // ===== scatter-max from accumulators (invP loads inline, unrolled) =====
  if (w < 6) {
    float betv[2];
    #pragma unroll
    for (int j = 0; j < 2; ++j) {
      int colb = wc4 * 32 + j * 16 + lr;
      betv[j] = (colb < 81) ? beta[colb] : 0.f;
    }
    #pragma unroll
    for (int i = 0; i < 3; ++i)
      #pragma unroll
      for (int r = 0; r < 4; ++r) {
        const int rowb = wr4 * 48 + i * 16 + (lg << 2) + r;
        if (rowb < 81) {
          const float av = alpha[rowb];
          #pragma unroll
          for (int j = 0; j < 2; ++j) {
            const int colb = wc4 * 32 + j * 16 + lr;
            if (colb < 81) {
              const u32 ev = encf(bd[i][j][r] * 0.0625f + av + betv[j]);
              const u32 pv = invP[rowb * 81 + colb];
              if (pv & 0xFFFFu) atomicMax(&pol[(pv & 0xFFFFu) - 1], ev);
              if (pv >> 16)     atomicMax(&pol[(pv >> 16) - 1], ev);
            }
          }
        } else if (rowb < 88) {
          const float dv = dqcS[rowb - 81];
          #pragma unroll
          for (int j = 0; j < 2; ++j) {
            const int colb = wc4 * 32 + j * 16 + lr;
            if (colb < 81)
              pol[1620 + (rowb - 81) * 81 + colb] = encf((bd[i][j][r] + dv) * 0.0625f);
          }
        }
      }
  }
  __syncthreads();   // bar4: pol complete

  // ===== decode + store =====
  if (isbf) {
    u16* ob = (u16*)out + (size_t)b * 2187u;
    for (int p2 = tid; p2 < 2187; p2 += 512) ob[p2] = f2b(decf(pol[p2]));
  } else {
    float* ob = (float*)out + (size_t)b * 2187u;
    for (int p2 = tid; p2 < 2187; p2 += 512) ob[p2] = decf(pol[p2]);
  }
}

// ---------------- launcher ----------------
extern "C" void kernel_launch(void* const* d_in, const int* in_sizes, int n_in,
                              void* d_out, int out_size, void* d_ws, size_t ws_size,
                              hipStream_t stream) {
  const void* x        = d_in[0];
  const void* W_embed  = d_in[1];
  const void* b_embed  = d_in[2];
  const void* Wq       = d_in[3];
  const void* bq       = d_in[4];
  const void* Wk       = d_in[5];
  const void* bk_      = d_in[6];
  const void* dq       = d_in[7];
  const int* valid_idx         = (const int*)d_in[8];
  const int* policy_idx        = (const int*)d_in[9];
  const int* promo_idx         = (const int*)d_in[10];
  const int* promo_policy_idx  = (const int*)d_in[11];
  const int n_valid = in_sizes[8];
  const int n_promo = in_sizes[10];
  const int B = in_sizes[0] / 20736;   // 81*256

  // ws layout
  char* ws = (char*)d_ws;
  u8t* Wt8    = (u8t*)(ws);               // 65536
  u8t* Wqk8   = (u8t*)(ws + 65536);       // 65536
  u8t* dqkp8  = (u8t*)(ws + 131072);      // 1792 (+pad)
  u8t* u8v    = (u8t*)(ws + 133120);      // 256
  u8t* w8v    = (u8t*)(ws + 133376);      // 256
  float* dqc  = (float*)(ws + 133632);    // 32
  int* dflag  = (int*)(ws + 133664);      // 32
  u32* invP   = (u32*)(ws + 133696);      // 26244
  if (ws_size < 160000) return;

  detect_dtype_kernel<<<dim3(1), dim3(256), 0, stream>>>(x, dflag);
  prep_wemb8<<<dim3(256), dim3(256), 0, stream>>>(W_embed, Wt8, dflag);
  prep_wqk8<<<dim3(256), dim3(256), 0, stream>>>(Wq, Wk, Wqk8, dflag);
  prep_vec8<<<dim3(9), dim3(256), 0, stream>>>(Wq, Wk, bq, bk_, dq,
                                               dqkp8, u8v, w8v, dqc, dflag);
  prep_invP<<<dim3(1), dim3(256), 0, stream>>>(
      valid_idx, policy_idx, promo_idx, promo_policy_idx, n_valid, n_promo, invP);

  (void)hipFuncSetAttribute((const void*)dirpolicy_fp8,
                            hipFuncAttributeMaxDynamicSharedMemorySize, LDS_TOTAL);
  if (B > 0)
    dirpolicy_fp8<<<dim3(B), dim3(512), LDS_TOTAL, stream>>>(
        x, b_embed, Wt8, Wqk8, dqkp8, u8v, w8v, dqc, invP, d_out, dflag);
}

// Round 7
// 347.829 us; speedup vs baseline: 3.4998x; 1.4101x over previous
//
#include <hip/hip_runtime.h>

typedef unsigned short u16;
typedef unsigned int u32;
typedef unsigned char u8t;
using bfrag = __attribute__((ext_vector_type(8))) short;   // 8 x bf16 (raw bits)
using facc  = __attribute__((ext_vector_type(4))) float;   // MFMA accumulator

// ---------------- numeric helpers ----------------
__device__ __forceinline__ u16 f2b(float f) {              // f32 -> bf16 (RNE)
  u32 u = __float_as_uint(f);
  return (u16)((u + 0x7FFFu + ((u >> 16) & 1u)) >> 16);
}
__device__ __forceinline__ float b2f(u16 h) { return __uint_as_float(((u32)h) << 16); }
__device__ __forceinline__ u32 encf(float f) {             // order-preserving f32->u32
  u32 u = __float_as_uint(f);
  return (u & 0x80000000u) ? ~u : (u | 0x80000000u);
}
__device__ __forceinline__ float decf(u32 e) {
  return __uint_as_float((e & 0x80000000u) ? (e & 0x7FFFFFFFu) : ~e);
}
__device__ __forceinline__ float mish_f(float v) {
  if (v > 15.f) return v;
  float ev = __expf(v);
  float p = ev * (ev + 2.f);
  return v * p / (p + 2.f);
}
__device__ __forceinline__ float ldf(const void* p, int i, int bf) {
  return bf ? b2f(((const u16*)p)[i]) : ((const float*)p)[i];
}
__device__ __forceinline__ u8t f2fp8(float f) {            // f32 -> fp8 e4m3 (OCP)
  return (u8t)(__builtin_amdgcn_cvt_pk_fp8_f32(f, f, 0, 0) & 0xFF);
}
// fp8 LDS tile: row stride 256B, XOR swizzle bits 4..6
__device__ __forceinline__ char* tp8(char* base, int row, int colb) {
  return base + ((row << 8) + (colb ^ ((row & 7) << 4)));
}

// ---------------- dtype detector ----------------
__global__ void detect_dtype_kernel(const void* __restrict__ x, int* __restrict__ flag) {
  __shared__ int cnt;
  const int tid = threadIdx.x;
  if (tid == 0) cnt = 0;
  __syncthreads();
  const u16* p = (const u16*)x;
  u16 h = p[tid * 96 + 4];
  int e = (int)((h >> 7) & 0xFF);
  if (e >= 116 && e <= 134) atomicAdd(&cnt, 1);
  __syncthreads();
  if (tid == 0) *flag = (cnt >= 128) ? 1 : 0;
}

// ---------------- consolidated prep (522 blocks, 256 thr) ----------------
// bid<256: W_embed[k=bid][n] -> fp8 fragment tiles Wt8
// bid<512: Wqk row n=bid-256 -> Wqk8 tiles
// bid<521: vec job blk=bid-512 (dqkp8 / u8v,w8v / dqc)
// bid==521: invP build
__global__ void prep_all(const void* __restrict__ W_embed,
                         const void* __restrict__ Wq, const void* __restrict__ Wk,
                         const void* __restrict__ bq, const void* __restrict__ bk,
                         const void* __restrict__ dq,
                         const int* __restrict__ vi, const int* __restrict__ pi,
                         const int* __restrict__ qi, const int* __restrict__ qpi,
                         int nv, int np,
                         u8t* __restrict__ Wt8, u8t* __restrict__ Wqk8,
                         u8t* __restrict__ dqkp8, u8t* __restrict__ u8v,
                         u8t* __restrict__ w8v, float* __restrict__ dqc,
                         u32* __restrict__ invP, const int* __restrict__ dflag) {
  __shared__ float wkrow[256];
  __shared__ u16 wqt[64][260];
  const int bid = blockIdx.x;
  const int bf = *dflag;
  const int t = threadIdx.x;

  if (bid < 256) {                 // ---- Wt8 tiles ----
    const int k = bid, n = t;
    u8t v = f2fp8(ldf(W_embed, (k << 8) + n, bf));
    int nt = n >> 4, lr = n & 15, kt = k >> 5, lg = (k >> 3) & 3, e = k & 7;
    Wt8[(((nt << 3) + kt) << 9) + (((lg << 4) + lr) << 3) + e] = v;
  } else if (bid < 512) {          // ---- Wqk8 tiles ----
    const int n = bid - 256, k = t;
    wkrow[k] = ldf(Wk, (n << 8) + k, bf);
    float s = 0.f;
    for (int d0 = 0; d0 < 256; d0 += 64) {
      __syncthreads();
      for (int it = 0; it < 64; ++it) {
        int kk = (it << 2) + (t >> 6);
        int dd = t & 63;
        wqt[dd][kk] = f2b(ldf(Wq, (kk << 8) + d0 + dd, bf));
      }
      __syncthreads();
      #pragma unroll 8
      for (int dd = 0; dd < 64; ++dd) s += b2f(wqt[dd][k]) * wkrow[d0 + dd];
    }
    int nt = n >> 4, lr = n & 15, kt = k >> 5, lg = (k >> 3) & 3, e = k & 7;
    Wqk8[(((nt << 3) + kt) << 9) + (((lg << 4) + lr) << 3) + e] = f2fp8(s);
  } else if (bid < 521) {          // ---- vectors ----
    const int blk = bid - 512, d = t;
    if (blk < 7) {
      float s = 0.f;
      for (int nn = 0; nn < 256; ++nn)
        s += ldf(Wk, (d << 8) + nn, bf) * ldf(dq, (blk << 8) + nn, bf);
      dqkp8[(blk << 8) + d] = f2fp8(s);
    } else if (blk == 7) {
      float su = 0.f, sw = 0.f;
      for (int nn = 0; nn < 256; ++nn) {
        su += ldf(Wq, (d << 8) + nn, bf) * ldf(bk, nn, bf);
        sw += ldf(Wk, (d << 8) + nn, bf) * ldf(bq, nn, bf);
      }
      u8v[d] = f2fp8(su); w8v[d] = f2fp8(sw);
    } else {
      if (d < 7) {
        float s = 0.f;
        for (int nn = 0; nn < 256; ++nn) s += ldf(dq, (d << 8) + nn, bf) * ldf(bk, nn, bf);
        dqc[d] = s;
      } else if (d == 7) {
        float s = 0.f;
        for (int nn = 0; nn < 256; ++nn) s += ldf(bq, nn, bf) * ldf(bk, nn, bf);
        dqc[7] = s;
      }
    }
  } else {                         // ---- invP ----
    for (int i = t; i < 6561; i += 256) invP[i] = 0u;
    __syncthreads();
    for (int i = t; i < nv; i += 256) atomicOr(&invP[vi[i]], (u32)(pi[i] + 1));
    for (int i = t; i < np; i += 256) atomicOr(&invP[qi[i]], ((u32)(qpi[i] + 1)) << 16);
  }
}

// ---------------- fused kernel: 256 thr, 1 element/block, 3 blocks/CU ----------------
// LDS (53324 B):
//   bufA @0      [90][256] fp8 swz  (x rows 0..80 -> T; rows 81..89 consts)
//   bufP @23040  [81][256] fp8 swz  (pe; fragment reads of rows 81..95 overflow
//                                    into pol region -> garbage feeding DISCARDED
//                                    board rows/cols >= 81..95 only)
//   pol  @43776  [2187] u32
//   alpha@52524  [96] f32 ; beta@52908 [96] f32 ; dqcS@53292 [8] f32
#define LDS_TOTAL 53504

__global__ __launch_bounds__(256, 2)   // 2 waves/EU hint -> VGPR cap ~128 (r6: 92 ok)
void dirpolicy_fp8(const void* __restrict__ x,
                   const void* __restrict__ b_embed,
                   const u8t* __restrict__ Wt8,
                   const u8t* __restrict__ Wqk8,
                   const u8t* __restrict__ dqkp8,
                   const u8t* __restrict__ u8v,
                   const u8t* __restrict__ w8v,
                   const float* __restrict__ dqc,
                   const u32* __restrict__ invP,
                   void* __restrict__ out,
                   const int* __restrict__ dflag) {
  extern __shared__ char smem[];
  char* bufA = smem;
  char* bufP = smem + 23040;
  u32* pol = (u32*)(smem + 43776);
  float* alpha = (float*)(smem + 52524);
  float* beta  = (float*)(smem + 52908);
  float* dqcS  = (float*)(smem + 53292);

  const int tid = threadIdx.x;
  const int lane = tid & 63;
  const int w = tid >> 6;          // wave 0..3
  const int lr = lane & 15;
  const int lg = lane >> 4;
  const int isbf = *dflag;
  const int b = blockIdx.x;
  const u32 ENEG = encf(-1e10f);

  // ---- prologue: consts + pol init ----
  for (int i = tid; i < 2304; i += 256) {      // bufA rows 81..89
    int q = i >> 8, d = i & 255;
    u8t bv = (q < 7) ? dqkp8[i] : ((q == 7) ? u8v[d] : w8v[d]);
    *tp8(bufA, 81 + q, d) = bv;
  }
  for (int i = tid; i < 2187; i += 256) pol[i] = ENEG;
  if (tid < 8) dqcS[tid] = dqc[tid];
  float biasv[4];
  #pragma unroll
  for (int j = 0; j < 4; ++j) biasv[j] = ldf(b_embed, (w << 6) + j * 16 + lr, isbf);

  // ---- stage x -> bufA rows 0..80 (fp8) ----
  if (isbf) {
    const u16* xb = (const u16*)x + (size_t)b * 20736u;
    #pragma unroll
    for (int c = 0; c < 11; ++c) {
      int idx = tid + (c << 8);
      if (idx < 2592) {
        bfrag v = *(const bfrag*)(xb + (idx << 3));
        u32 lo = __builtin_amdgcn_cvt_pk_fp8_f32(b2f((u16)v[0]), b2f((u16)v[1]), 0, 0);
        lo = __builtin_amdgcn_cvt_pk_fp8_f32(b2f((u16)v[2]), b2f((u16)v[3]), lo, 1);
        u32 hi = __builtin_amdgcn_cvt_pk_fp8_f32(b2f((u16)v[4]), b2f((u16)v[5]), 0, 0);
        hi = __builtin_amdgcn_cvt_pk_fp8_f32(b2f((u16)v[6]), b2f((u16)v[7]), hi, 1);
        uint2 pk; pk.x = lo; pk.y = hi;
        *(uint2*)tp8(bufA, idx >> 5, (idx & 31) << 3) = pk;
      }
    }
  } else {
    const float4* xs = (const float4*)((const float*)x + (size_t)b * 20736u);
    #pragma unroll
    for (int c = 0; c < 11; ++c) {
      int idx = tid + (c << 8);
      if (idx < 2592) {
        float4 p0 = xs[idx * 2], p1 = xs[idx * 2 + 1];
        u32 lo = __builtin_amdgcn_cvt_pk_fp8_f32(p0.x, p0.y, 0, 0);
        lo = __builtin_amdgcn_cvt_pk_fp8_f32(p0.z, p0.w, lo, 1);
        u32 hi = __builtin_amdgcn_cvt_pk_fp8_f32(p1.x, p1.y, 0, 0);
        hi = __builtin_amdgcn_cvt_pk_fp8_f32(p1.z, p1.w, hi, 1);
        uint2 pk; pk.x = lo; pk.y = hi;
        *(uint2*)tp8(bufA, idx >> 5, (idx & 31) << 3) = pk;
      }
    }
  }
  __syncthreads();   // bar0

  // ===== phase 1: pe = mish(x @ We + b) -> bufP; wave w = cols w*64..+63,
  //       two row-half passes (rows rh*48..+47) =====
  for (int rh = 0; rh < 2; ++rh) {
    facc acc[3][4];
    facc z4 = {0.f, 0.f, 0.f, 0.f};
    #pragma unroll
    for (int i = 0; i < 3; ++i)
      #pragma unroll
      for (int j = 0; j < 4; ++j) acc[i][j] = z4;
    #pragma unroll
    for (int kt = 0; kt < 8; ++kt) {
      long bb[4], a[3];
      #pragma unroll
      for (int j = 0; j < 4; ++j)
        bb[j] = *(const long*)(Wt8 + (((((w << 2) + j) << 3) + kt) << 9) + (lane << 3));
      #pragma unroll
      for (int i = 0; i < 3; ++i)
        a[i] = *(const long*)tp8(bufA, rh * 48 + i * 16 + lr, (kt << 5) + (lg << 3));
      #pragma unroll
      for (int i = 0; i < 3; ++i)
        #pragma unroll
        for (int j = 0; j < 4; ++j)
          acc[i][j] = __builtin_amdgcn_mfma_f32_16x16x32_fp8_fp8(a[i], bb[j], acc[i][j], 0, 0, 0);
    }
    #pragma unroll
    for (int j = 0; j < 4; ++j) {
      const int col = (w << 6) + j * 16 + lr;
      #pragma unroll
      for (int i = 0; i < 3; ++i)
        #pragma unroll
        for (int r = 0; r < 4; ++r) {
          const int row = rh * 48 + i * 16 + (lg << 2) + r;
          if (row < 81)
            *tp8(bufP, row, col) = f2fp8(mish_f(acc[i][j][r] + biasv[j]));
        }
    }
  }
  __syncthreads();   // bar1: pe complete; bufA rows<81 free

  // ===== phase 3: T = pe @ Wqk -> bufA rows 0..80 =====
  for (int rh = 0; rh < 2; ++rh) {
    facc acc2[3][4];
    facc z4 = {0.f, 0.f, 0.f, 0.f};
    #pragma unroll
    for (int i = 0; i < 3; ++i)
      #pragma unroll
      for (int j = 0; j < 4; ++j) acc2[i][j] = z4;
    #pragma unroll
    for (int kt = 0; kt < 8; ++kt) {
      long bb[4], a[3];
      #pragma unroll
      for (int j = 0; j < 4; ++j)
        bb[j] = *(const long*)(Wqk8 + (((((w << 2) + j) << 3) + kt) << 9) + (lane << 3));
      #pragma unroll
      for (int i = 0; i < 3; ++i)
        a[i] = *(const long*)tp8(bufP, rh * 48 + i * 16 + lr, (kt << 5) + (lg << 3));
      #pragma unroll
      for (int i = 0; i < 3; ++i)
        #pragma unroll
        for (int j = 0; j < 4; ++j)
          acc2[i][j] = __builtin_amdgcn_mfma_f32_16x16x32_fp8_fp8(a[i], bb[j], acc2[i][j], 0, 0, 0);
    }
    #pragma unroll
    for (int j = 0; j < 4; ++j) {
      const int col = (w << 6) + j * 16 + lr;
      #pragma unroll
      for (int i = 0; i < 3; ++i)
        #pragma unroll
        for (int r = 0; r < 4; ++r) {
          const int row = rh * 48 + i * 16 + (lg << 2) + r;
          if (row < 81) *tp8(bufA, row, col) = f2fp8(acc2[i][j][r]);
        }
    }
  }
  __syncthreads();   // bar2: T visible

  // ===== phase 4: board = [T;dqkp;u;w] @ pe^T, 2x2 wave grid =====
  const int wr4 = w >> 1;          // rows wr4*48..+47
  const int wc4 = w & 1;           // cols wc4*48..+47
  facc bd[3][3];
  {
    facc z4 = {0.f, 0.f, 0.f, 0.f};
    #pragma unroll
    for (int i = 0; i < 3; ++i)
      #pragma unroll
      for (int j = 0; j < 3; ++j) bd[i][j] = z4;
  }
  #pragma unroll
  for (int kt = 0; kt < 8; ++kt) {
    long a[3], bb[3];
    #pragma unroll
    for (int i = 0; i < 3; ++i)
      a[i] = *(const long*)tp8(bufA, wr4 * 48 + i * 16 + lr, (kt << 5) + (lg << 3));
    #pragma unroll
    for (int j = 0; j < 3; ++j)
      bb[j] = *(const long*)tp8(bufP, wc4 * 48 + j * 16 + lr, (kt << 5) + (lg << 3));
    #pragma unroll
    for (int i = 0; i < 3; ++i)
      #pragma unroll
      for (int j = 0; j < 3; ++j)
        bd[i][j] = __builtin_amdgcn_mfma_f32_16x16x32_fp8_fp8(a[i], bb[j], bd[i][j], 0, 0, 0);
  }
  // board rows 88/89 (u,w) -> alpha/beta (writers: wr4==1, i==2, lg==2, r=0/1)
  if (wr4 == 1 && lg == 2) {
    const float c7 = dqcS[7];
    #pragma unroll
    for (int j = 0; j < 3; ++j) {
      const int colb = wc4 * 48 + j * 16 + lr;
      alpha[colb] = (bd[2][j][0] + c7) * 0.0625f;
      beta[colb]  = bd[2][j][1] * 0.0625f;
    }
  }
  __syncthreads();   // bar3: alpha/beta visible

  // ===== scatter-max from accumulators =====
  {
    float betv[3];
    #pragma unroll
    for (int j = 0; j < 3; ++j) {
      int colb = wc4 * 48 + j * 16 + lr;
      betv[j] = (colb < 81) ? beta[colb] : 0.f;
    }
    #pragma unroll
    for (int i = 0; i < 3; ++i)
      #pragma unroll
      for (int r = 0; r < 4; ++r) {
        const int rowb = wr4 * 48 + i * 16 + (lg << 2) + r;
        if (rowb < 81) {
          const float av = alpha[rowb];
          #pragma unroll
          for (int j = 0; j < 3; ++j) {
            const int colb = wc4 * 48 + j * 16 + lr;
            if (colb < 81) {
              const u32 ev = encf(bd[i][j][r] * 0.0625f + av + betv[j]);
              const u32 pv = invP[rowb * 81 + colb];
              if (pv & 0xFFFFu) atomicMax(&pol[(pv & 0xFFFFu) - 1], ev);
              if (pv >> 16)     atomicMax(&pol[(pv >> 16) - 1], ev);
            }
          }
        } else if (rowb < 88) {
          const float dv = dqcS[rowb - 81];
          #pragma unroll
          for (int j = 0; j < 3; ++j) {
            const int colb = wc4 * 48 + j * 16 + lr;
            if (colb < 81)
              pol[1620 + (rowb - 81) * 81 + colb] = encf((bd[i][j][r] + dv) * 0.0625f);
          }
        }
      }
  }
  __syncthreads();   // bar4: pol complete

  // ===== decode + store =====
  if (isbf) {
    u16* ob = (u16*)out + (size_t)b * 2187u;
    for (int p2 = tid; p2 < 2187; p2 += 256) ob[p2] = f2b(decf(pol[p2]));
  } else {
    float* ob = (float*)out + (size_t)b * 2187u;
    for (int p2 = tid; p2 < 2187; p2 += 256) ob[p2] = decf(pol[p2]);
  }
}

// ---------------- launcher ----------------
extern "C" void kernel_launch(void* const* d_in, const int* in_sizes, int n_in,
                              void* d_out, int out_size, void* d_ws, size_t ws_size,
                              hipStream_t stream) {
  const void* x        = d_in[0];
  const void* W_embed  = d_in[1];
  const void* b_embed  = d_in[2];
  const void* Wq       = d_in[3];
  const void* bq       = d_in[4];
  const void* Wk       = d_in[5];
  const void* bk_      = d_in[6];
  const void* dq       = d_in[7];
  const int* valid_idx         = (const int*)d_in[8];
  const int* policy_idx        = (const int*)d_in[9];
  const int* promo_idx         = (const int*)d_in[10];
  const int* promo_policy_idx  = (const int*)d_in[11];
  const int n_valid = in_sizes[8];
  const int n_promo = in_sizes[10];
  const int B = in_sizes[0] / 20736;   // 81*256

  // ws layout
  char* ws = (char*)d_ws;
  u8t* Wt8    = (u8t*)(ws);               // 65536
  u8t* Wqk8   = (u8t*)(ws + 65536);       // 65536
  u8t* dqkp8  = (u8t*)(ws + 131072);      // 1792 (+pad)
  u8t* u8v    = (u8t*)(ws + 133120);      // 256
  u8t* w8v    = (u8t*)(ws + 133376);      // 256
  float* dqc  = (float*)(ws + 133632);    // 32
  int* dflag  = (int*)(ws + 133664);      // 32
  u32* invP   = (u32*)(ws + 133696);      // 26244
  if (ws_size < 160000) return;

  detect_dtype_kernel<<<dim3(1), dim3(256), 0, stream>>>(x, dflag);
  prep_all<<<dim3(522), dim3(256), 0, stream>>>(
      W_embed, Wq, Wk, bq, bk_, dq,
      valid_idx, policy_idx, promo_idx, promo_policy_idx, n_valid, n_promo,
      Wt8, Wqk8, dqkp8, u8v, w8v, dqc, invP, dflag);

  (void)hipFuncSetAttribute((const void*)dirpolicy_fp8,
                            hipFuncAttributeMaxDynamicSharedMemorySize, LDS_TOTAL);
  if (B > 0)
    dirpolicy_fp8<<<dim3(B), dim3(256), LDS_TOTAL, stream>>>(
        x, b_embed, Wt8, Wqk8, dqkp8, u8v, w8v, dqc, invP, d_out, dflag);
}